// Round 11
// baseline (458.626 us; speedup 1.0000x reference)
//
#include <hip/hip_runtime.h>
#include <hip/hip_cooperative_groups.h>
#include <math.h>

namespace cg = cooperative_groups;

#define NSEG 7320
#define NLON 120
#define HIDN 128
#define ECH  16     // entries per attention work item (R9-proven)
#define NRCH 48     // chunks per row cap: 48*16=768 >= max row ~520
#define NTILE 29    // 29*256 = 7424 >= NSEG point tiles

// ---------------------------------------------------------------------------
// Single persistent cooperative kernel. Phases separated by grid.sync():
//  P1: zero num/den + meta/row_start build + LN0+QKV (planar [64][NSEG])
//  P2: attention (row,chunk,head) items — R9's exact 43us shape
//  P3: att=num/den -> Wo + residual -> x1
//  P4: LN1 + W1 + exact gelu -> m_act
//  P5: W2 + b2 + x1 -> out
// All phases stream channels: per-thread arrays <= 32 floats (no spill;
// R7/R8/R10 lesson). Weights read wave-uniform (s_load broadcast).
// __launch_bounds__(256,2) caps VGPR at 256 -> 512 blocks guaranteed
// co-resident on 256 CUs (cooperative launch requirement).
// ---------------------------------------------------------------------------
__global__ __launch_bounds__(256, 2) void mega(
    const float* __restrict__ x,
    const float* __restrict__ wq, const float* __restrict__ wk,
    const float* __restrict__ wv, const float* __restrict__ wo,
    const float* __restrict__ w1, const float* __restrict__ b1,
    const float* __restrict__ w2, const float* __restrict__ b2,
    const float* __restrict__ ln0g, const float* __restrict__ ln0b,
    const float* __restrict__ ln1g, const float* __restrict__ ln1b,
    const float* __restrict__ qw,
    const int* __restrict__ out_idx, const int* __restrict__ in_idx,
    int E,
    float* __restrict__ q_pl, float* __restrict__ k_pl, float* __restrict__ v_pl,
    float* __restrict__ num,  float* __restrict__ den,
    float* __restrict__ x1,   float* __restrict__ m_act,
    int* __restrict__ row_start, int4* __restrict__ meta,
    float* __restrict__ out)
{
    cg::grid_group grid = cg::this_grid();
    const int tid = threadIdx.x;
    const int nb  = gridDim.x;
    const int gid = blockIdx.x * 256 + tid;
    const int gsz = nb * 256;

    // ---------------- P1a: zero num[64][NSEG] + den[4][NSEG] ----------------
    {
        float4* z = (float4*)num;              // den contiguous after num
        const int n4 = (68 * NSEG) / 4;
        for (int i = gid; i < n4; i += gsz)
            z[i] = make_float4(0.f, 0.f, 0.f, 0.f);
    }
    // ---------------- P1b: meta + row_start -------------------------------
    for (int e = gid; e < E; e += gsz) {
        int ho = out_idx[e * NLON] / NLON;
        if (e == 0) {
            row_start[ho] = 0;
        } else {
            int hp = out_idx[(e - 1) * NLON] / NLON;
            if (hp != ho) row_start[ho] = e;
        }
        if (e == E - 1) row_start[ho + 1] = E;
        int i0 = in_idx[e * NLON];             // wo=0 column: hi*120 + dl
        int hi = i0 / NLON;
        int dl = i0 - hi * NLON;
        meta[e] = make_int4(hi * NLON, dl, __float_as_int(qw[i0]), ho);
    }
    // ---------------- P1c: LN0 + QKV (streamed, acc[8]) -------------------
    for (int it = blockIdx.x; it < NTILE * 24; it += nb) {
        int tile = it % NTILE, grp = it / NTILE;
        int n = tile * 256 + tid;
        bool act = n < NSEG;
        int nn = act ? n : (NSEG - 1);

        float s = 0.f, s2 = 0.f;
        for (int c = 0; c < 64; ++c) { float t = x[c * NSEG + nn]; s += t; s2 += t * t; }
        float mean = s * 0.015625f;
        float var  = s2 * 0.015625f - mean * mean;
        float r    = rsqrtf(var + 1e-6f);

        int mm = grp >> 3, ob = (grp & 7) * 8;
        const float* __restrict__ w = (mm == 0) ? wq : (mm == 1) ? wk : wv;
        float* __restrict__ dst = (mm == 0) ? q_pl : (mm == 1) ? k_pl : v_pl;
        float scale = (mm == 0) ? 0.25f : 1.0f;   // fold 1/sqrt(DH) into q

        float acc[8];
#pragma unroll
        for (int j = 0; j < 8; ++j) acc[j] = 0.f;
        for (int c = 0; c < 64; ++c) {
            float xh = (x[c * NSEG + nn] - mean) * r * ln0g[c] + ln0b[c];
            const float* __restrict__ wc = w + ob * 64 + c;   // uniform
#pragma unroll
            for (int j = 0; j < 8; ++j) acc[j] = fmaf(wc[j * 64], xh, acc[j]);
        }
        if (act)
#pragma unroll
            for (int j = 0; j < 8; ++j) dst[(ob + j) * NSEG + n] = acc[j] * scale;
    }
    grid.sync();

    // ---------------- P2: attention (row,chunk,head), 2 items/block --------
    {
        const int total = 61 * NRCH * 4;
        const int sub = tid >> 7;              // 0/1 (wave-aligned)
        const int wol = tid & 127;
        const bool aw = wol < NLON;
        const int woc = aw ? wol : (NLON - 1);
        for (int base = blockIdx.x * 2; base < total; base += nb * 2) {
            int item = base + sub;
            if (item >= total) continue;
            int row  = item % 61;
            int rest = item / 61;
            int chunk = rest % NRCH;
            int head  = rest / NRCH;
            int e0 = __builtin_amdgcn_readfirstlane(row_start[row]);
            int e1 = __builtin_amdgcn_readfirstlane(row_start[row + 1]);
            int eb = e0 + chunk * ECH;
            if (eb >= e1) continue;
            int ee = eb + ECH; if (ee > e1) ee = e1;

            const int cb = head * 16;
            const int segc = row * NLON + woc;
            const float* __restrict__ qb = q_pl + (size_t)cb * NSEG;
            const float* __restrict__ kb = k_pl + (size_t)cb * NSEG;
            const float* __restrict__ vb = v_pl + (size_t)cb * NSEG;

            float qreg[16];
#pragma unroll
            for (int c = 0; c < 16; ++c) qreg[c] = qb[c * NSEG + segc];
            float acc[16];
#pragma unroll
            for (int c = 0; c < 16; ++c) acc[c] = 0.f;
            float dh = 0.f;

#pragma unroll 2
            for (int e = eb; e < ee; ++e) {
                int4 mt = meta[e];
                int dlw = mt.y + woc; if (dlw >= NLON) dlw -= NLON;
                const float* __restrict__ kp = kb + (mt.x + dlw);
                const float* __restrict__ vp = vb + (mt.x + dlw);
                float sa = 0.f, sb = 0.f;
#pragma unroll
                for (int c = 0; c < 8; ++c) sa += qreg[c]     * kp[c * NSEG];
#pragma unroll
                for (int c = 0; c < 8; ++c) sb += qreg[8 + c] * kp[(8 + c) * NSEG];
                float qwv = aw ? __int_as_float(mt.z) : 0.f;
                float a = __expf(sa + sb) * qwv;   // no-max softmax (R2..R9)
                dh += a;
#pragma unroll
                for (int c = 0; c < 16; ++c) acc[c] = fmaf(a, vp[c * NSEG], acc[c]);
            }
            if (aw) {
                const int seg = row * NLON + wol;
#pragma unroll
                for (int c = 0; c < 16; ++c)
                    atomicAdd(&num[(cb + c) * NSEG + seg], acc[c]);
                atomicAdd(&den[head * NSEG + seg], dh);
            }
        }
    }
    grid.sync();

    // ---------------- P3: att=num/den -> Wo + residual -> x1 ---------------
    for (int it = blockIdx.x; it < NTILE * 8; it += nb) {
        int tile = it % NTILE, og = it / NTILE;
        int n = tile * 256 + tid;
        if (n >= NSEG) continue;
        float rdh[4];
#pragma unroll
        for (int h = 0; h < 4; ++h) rdh[h] = 1.0f / den[h * NSEG + n];
        const int o0 = og * 8;
        float acc[8];
#pragma unroll
        for (int j = 0; j < 8; ++j) acc[j] = 0.f;
        for (int c = 0; c < 64; ++c) {
            float a = num[c * NSEG + n] * rdh[c >> 4];
            const float* __restrict__ wc = wo + o0 * 64 + c;  // uniform
#pragma unroll
            for (int j = 0; j < 8; ++j) acc[j] = fmaf(wc[j * 64], a, acc[j]);
        }
#pragma unroll
        for (int j = 0; j < 8; ++j)
            x1[(o0 + j) * NSEG + n] = acc[j] + x[(o0 + j) * NSEG + n];
    }
    grid.sync();

    // ---------------- P4: LN1 + W1 + exact gelu -> m_act -------------------
    for (int it = blockIdx.x; it < NTILE * 8; it += nb) {
        int tile = it % NTILE, hg = it / NTILE;
        int n = tile * 256 + tid;
        if (n >= NSEG) continue;
        float s = 0.f, s2 = 0.f;
        for (int c = 0; c < 64; ++c) { float t = x1[c * NSEG + n]; s += t; s2 += t * t; }
        float mean = s * 0.015625f;
        float var  = s2 * 0.015625f - mean * mean;
        float r    = rsqrtf(var + 1e-6f);
        const int h0 = hg * 16;
        float mh[16];
#pragma unroll
        for (int j = 0; j < 16; ++j) mh[j] = b1[h0 + j];
        for (int c = 0; c < 64; ++c) {
            float xn = (x1[c * NSEG + n] - mean) * r * ln1g[c] + ln1b[c];
            const float* __restrict__ wc = w1 + h0 * 64 + c;  // uniform
#pragma unroll
            for (int j = 0; j < 16; ++j) mh[j] = fmaf(wc[j * 64], xn, mh[j]);
        }
#pragma unroll
        for (int j = 0; j < 16; ++j)
            m_act[(h0 + j) * NSEG + n] =
                0.5f * mh[j] * (1.0f + erff(mh[j] * 0.70710678118654752f));
    }
    grid.sync();

    // ---------------- P5: W2 + b2 + x1 -> out ------------------------------
    for (int it = blockIdx.x; it < NTILE * 8; it += nb) {
        int tile = it % NTILE, cgp = it / NTILE;
        int n = tile * 256 + tid;
        if (n >= NSEG) continue;
        const int c0 = cgp * 8;
        float acc[8];
#pragma unroll
        for (int j = 0; j < 8; ++j) acc[j] = 0.f;
#pragma unroll 8
        for (int h = 0; h < HIDN; ++h) {
            float mh = m_act[h * NSEG + n];
            const float* __restrict__ wc = w2 + c0 * HIDN + h; // uniform
#pragma unroll
            for (int j = 0; j < 8; ++j) acc[j] = fmaf(wc[j * HIDN], mh, acc[j]);
        }
#pragma unroll
        for (int j = 0; j < 8; ++j) {
            int c = c0 + j;
            out[c * NSEG + n] = acc[j] + b2[c] + x1[c * NSEG + n];
        }
    }
}

// ---------------------------------------------------------------------------
extern "C" void kernel_launch(void* const* d_in, const int* in_sizes, int n_in,
                              void* d_out, int out_size, void* d_ws, size_t ws_size,
                              hipStream_t stream)
{
    const float* x    = (const float*)d_in[0];
    const float* wq   = (const float*)d_in[1];
    const float* wk   = (const float*)d_in[2];
    const float* wv   = (const float*)d_in[3];
    const float* wo   = (const float*)d_in[4];
    const float* w1   = (const float*)d_in[5];
    const float* b1   = (const float*)d_in[6];
    const float* w2   = (const float*)d_in[7];
    const float* b2   = (const float*)d_in[8];
    const float* ln0g = (const float*)d_in[9];
    const float* ln0b = (const float*)d_in[10];
    const float* ln1g = (const float*)d_in[11];
    const float* ln1b = (const float*)d_in[12];
    const float* qw   = (const float*)d_in[13];
    const int* out_idx = (const int*)d_in[14];
    const int* in_idx  = (const int*)d_in[15];
    float* out = (float*)d_out;

    int E = in_sizes[15] / NLON;
    const size_t N64 = (size_t)NSEG * 64;

    float* ws    = (float*)d_ws;
    float* q_pl  = ws;                       // [64][NSEG]
    float* k_pl  = ws + N64;
    float* v_pl  = ws + 2 * N64;
    float* num   = ws + 3 * N64;             // [64][NSEG] (zeroed in P1)
    float* den   = ws + 4 * N64;             // [4][NSEG]  (contiguous w/ num)
    float* x1    = ws + 4 * N64 + 4 * NSEG;
    float* m_act = ws + 5 * N64 + 4 * NSEG;  // [128][NSEG]
    int*   row_start = (int*)(ws + 7 * N64 + 4 * NSEG);       // [62]
    int4*  meta  = (int4*)(ws + 7 * N64 + 4 * NSEG + 64);     // [E]

    void* args[] = {
        (void*)&x, (void*)&wq, (void*)&wk, (void*)&wv, (void*)&wo,
        (void*)&w1, (void*)&b1, (void*)&w2, (void*)&b2,
        (void*)&ln0g, (void*)&ln0b, (void*)&ln1g, (void*)&ln1b,
        (void*)&qw, (void*)&out_idx, (void*)&in_idx, (void*)&E,
        (void*)&q_pl, (void*)&k_pl, (void*)&v_pl,
        (void*)&num, (void*)&den, (void*)&x1, (void*)&m_act,
        (void*)&row_start, (void*)&meta, (void*)&out
    };
    hipLaunchCooperativeKernel((const void*)mega, dim3(512), dim3(256),
                               args, 0, stream);
}

// Round 12
// 259.530 us; speedup vs baseline: 1.7671x; 1.7671x over previous
//
#include <hip/hip_runtime.h>
#include <math.h>

#define NSEG 7320
#define NLON 120
#define HIDN 128

// ---------------------------------------------------------------------------
// K1: grp 0-23: LN0 + QKV projection (8 output channels per group), planar
// [64][NSEG] outputs, coalesced. q pre-scaled by 1/sqrt(DH)=0.25.
// grp 24: meta {hi*120, dl, qw bits, ho} + per-lat-row CSR offsets.
// (num/den zero-init removed — K2 now writes them exactly once.)
// ---------------------------------------------------------------------------
__global__ __launch_bounds__(64) void k1_ln_qkv(
    const float* __restrict__ x,  const float* __restrict__ wq,
    const float* __restrict__ wk, const float* __restrict__ wv,
    const float* __restrict__ g,  const float* __restrict__ b,
    const int* __restrict__ out_idx, const int* __restrict__ in_idx,
    const float* __restrict__ qw, int E,
    float* __restrict__ q_pl, float* __restrict__ k_pl, float* __restrict__ v_pl,
    int* __restrict__ row_start, int4* __restrict__ meta)
{
    const int lane = threadIdx.x;
    const int tile = blockIdx.x;
    const int grp  = blockIdx.y;

    if (grp == 24) {                       // meta + row_start build
        for (int e = tile * 64 + lane; e < E; e += 115 * 64) {
            int ho = out_idx[e * NLON] / NLON;
            if (e == 0) {
                row_start[ho] = 0;
            } else {
                int hp = out_idx[(e - 1) * NLON] / NLON;
                if (hp != ho) row_start[ho] = e;
            }
            if (e == E - 1) row_start[ho + 1] = E;
            int i0 = in_idx[e * NLON];     // wo = 0 column: hi*120 + dl
            int hi = i0 / NLON;
            int dl = i0 - hi * NLON;
            meta[e] = make_int4(hi * NLON, dl, __float_as_int(qw[i0]), ho);
        }
        return;
    }

    const int n = tile * 64 + lane;
    if (n >= NSEG) return;

    float xv[64];
    float s = 0.f, s2 = 0.f;
#pragma unroll
    for (int c = 0; c < 64; ++c) { float t = x[c * NSEG + n]; xv[c] = t; s += t; s2 += t * t; }
    float mean = s * 0.015625f;
    float var  = s2 * 0.015625f - mean * mean;
    float rstd = rsqrtf(var + 1e-6f);
#pragma unroll
    for (int c = 0; c < 64; ++c) xv[c] = (xv[c] - mean) * rstd * g[c] + b[c];

    const int mm    = grp >> 3;            // 0=q 1=k 2=v
    const int obase = (grp & 7) * 8;
    const float* __restrict__ w = (mm == 0) ? wq : (mm == 1) ? wk : wv;
    float* __restrict__ dst = (mm == 0) ? q_pl : (mm == 1) ? k_pl : v_pl;
    const float scale = (mm == 0) ? 0.25f : 1.0f;

#pragma unroll
    for (int j = 0; j < 8; ++j) {
        int o = obase + j;
        float acc = 0.f;
#pragma unroll
        for (int c = 0; c < 64; ++c) acc += w[o * 64 + c] * xv[c];
        dst[o * NSEG + n] = acc * scale;
    }
}

// ---------------------------------------------------------------------------
// K2: fused scores + PV, one (row, head) per block — ZERO global atomics.
// 512 thr = 4 subgroups of 128 lanes (lane = wo); subgroup s processes
// entries e0+s, e0+s+4, ... with R9's proven per-lane body (16-ch dot,
// exp, 16 fma; ~60 VGPR). LDS reduce (4 x 17 x 128 = 34 KB) merges the 4
// subgroup partials; subgroup 0 writes num/den exactly once, coalesced.
// Rationale: R9/R10 WRITE_SIZE 17.5 MB = ~9x num+den size — device-scope
// atomicAdd partials from blocks on different XCDs flush per contributor
// (~33 us of k2's 43 us). No zero-init needed. No-max softmax (R2..R9).
// ---------------------------------------------------------------------------
__global__ __launch_bounds__(512) void k2_attn(
    const float* __restrict__ q_pl, const float* __restrict__ k_pl,
    const float* __restrict__ v_pl,
    const int4* __restrict__ meta,  const int* __restrict__ row_start,
    float* __restrict__ num, float* __restrict__ den)
{
    __shared__ float lds[4][17][128];

    const int tid = threadIdx.x;
    const int sub = tid >> 7;              // 0..3
    const int wol = tid & 127;
    const bool aw = wol < NLON;
    const int woc = aw ? wol : (NLON - 1);
    const int ho   = blockIdx.x;
    const int head = blockIdx.y;
    const int cb   = head * 16;

    int e0 = __builtin_amdgcn_readfirstlane(row_start[ho]);
    int e1 = __builtin_amdgcn_readfirstlane(row_start[ho + 1]);

    const int segc = ho * NLON + woc;
    const float* __restrict__ qb = q_pl + (size_t)cb * NSEG;
    const float* __restrict__ kb = k_pl + (size_t)cb * NSEG;
    const float* __restrict__ vb = v_pl + (size_t)cb * NSEG;

    float qreg[16];
#pragma unroll
    for (int c = 0; c < 16; ++c) qreg[c] = qb[c * NSEG + segc];

    float acc[16];
#pragma unroll
    for (int c = 0; c < 16; ++c) acc[c] = 0.f;
    float dh = 0.f;

#pragma unroll 2
    for (int e = e0 + sub; e < e1; e += 4) {
        int4 mt = meta[e];
        int dlw = mt.y + woc; if (dlw >= NLON) dlw -= NLON;
        const float* __restrict__ kp = kb + (mt.x + dlw);
        const float* __restrict__ vp = vb + (mt.x + dlw);

        float sa = 0.f, sb = 0.f;
#pragma unroll
        for (int c = 0; c < 8; ++c)  sa += qreg[c]     * kp[c * NSEG];
#pragma unroll
        for (int c = 0; c < 8; ++c)  sb += qreg[8 + c] * kp[(8 + c) * NSEG];

        float qwv = aw ? __int_as_float(mt.z) : 0.f;
        float a = __expf(sa + sb) * qwv;
        dh += a;

#pragma unroll
        for (int c = 0; c < 16; ++c) acc[c] = fmaf(a, vp[c * NSEG], acc[c]);
    }

#pragma unroll
    for (int c = 0; c < 16; ++c) lds[sub][c][wol] = acc[c];
    lds[sub][16][wol] = dh;
    __syncthreads();

    if (sub == 0 && aw) {
        const int seg = ho * NLON + wol;
#pragma unroll
        for (int c = 0; c < 16; ++c) {
            float sm = lds[0][c][wol] + lds[1][c][wol]
                     + lds[2][c][wol] + lds[3][c][wol];
            num[(cb + c) * NSEG + seg] = sm;
        }
        den[head * NSEG + seg] = lds[0][16][wol] + lds[1][16][wol]
                               + lds[2][16][wol] + lds[3][16][wol];
    }
}

// ---------------------------------------------------------------------------
// K2c: att = num/den, Wo projection + residual -> x1 planar.
// grid (115, 8): 8 output channels per group; thread-per-point, all planar.
// ---------------------------------------------------------------------------
__global__ __launch_bounds__(64) void k2c_wo(
    const float* __restrict__ num, const float* __restrict__ den,
    const float* __restrict__ wo,  const float* __restrict__ x,
    float* __restrict__ x1)
{
    const int lane = threadIdx.x;
    const int n    = blockIdx.x * 64 + lane;
    if (n >= NSEG) return;

    float rdh[4];
#pragma unroll
    for (int h = 0; h < 4; ++h) rdh[h] = 1.0f / den[h * NSEG + n];

    float att[64];
#pragma unroll
    for (int c = 0; c < 64; ++c) att[c] = num[c * NSEG + n] * rdh[c >> 4];

    const int o0 = blockIdx.y * 8;
#pragma unroll
    for (int j = 0; j < 8; ++j) {
        int o = o0 + j;
        float acc = 0.f;
#pragma unroll
        for (int c = 0; c < 64; ++c) acc += wo[o * 64 + c] * att[c];
        x1[o * NSEG + n] = acc + x[o * NSEG + n];
    }
}

// ---------------------------------------------------------------------------
// K3a: LayerNorm1 + W1 + exact gelu -> m_act planar [128][NSEG].
// grid (115, 8): 16 hidden units per group.
// ---------------------------------------------------------------------------
__global__ __launch_bounds__(64) void k3a_mlp1(
    const float* __restrict__ x1, const float* __restrict__ w1,
    const float* __restrict__ b1, const float* __restrict__ g,
    const float* __restrict__ bb, float* __restrict__ m_act)
{
    const int lane = threadIdx.x;
    const int n    = blockIdx.x * 64 + lane;
    if (n >= NSEG) return;

    float xv[64];
    float s = 0.f, s2 = 0.f;
#pragma unroll
    for (int c = 0; c < 64; ++c) { float t = x1[c * NSEG + n]; xv[c] = t; s += t; s2 += t * t; }
    float mean = s * 0.015625f;
    float var  = s2 * 0.015625f - mean * mean;
    float rstd = rsqrtf(var + 1e-6f);
#pragma unroll
    for (int c = 0; c < 64; ++c) xv[c] = (xv[c] - mean) * rstd * g[c] + bb[c];

    const int h0 = blockIdx.y * 16;
#pragma unroll
    for (int j = 0; j < 16; ++j) {
        int h = h0 + j;
        float mh = b1[h];
#pragma unroll
        for (int c = 0; c < 64; ++c) mh += w1[h * 64 + c] * xv[c];
        m_act[h * NSEG + n] = 0.5f * mh * (1.0f + erff(mh * 0.70710678118654752f));
    }
}

// ---------------------------------------------------------------------------
// K3b: out = W2 * m_act + b2 + x1. grid (115, 8): 8 output channels/group.
// ---------------------------------------------------------------------------
__global__ __launch_bounds__(64) void k3b_mlp2(
    const float* __restrict__ m_act, const float* __restrict__ w2,
    const float* __restrict__ b2,    const float* __restrict__ x1,
    float* __restrict__ out)
{
    const int lane = threadIdx.x;
    const int n    = blockIdx.x * 64 + lane;
    if (n >= NSEG) return;
    const int c0   = blockIdx.y * 8;

    float acc[8];
#pragma unroll
    for (int j = 0; j < 8; ++j) acc[j] = 0.f;

#pragma unroll 8
    for (int h = 0; h < HIDN; ++h) {
        float mh = m_act[h * NSEG + n];
#pragma unroll
        for (int j = 0; j < 8; ++j) acc[j] += w2[(c0 + j) * HIDN + h] * mh;
    }
#pragma unroll
    for (int j = 0; j < 8; ++j) {
        int c = c0 + j;
        out[c * NSEG + n] = acc[j] + b2[c] + x1[c * NSEG + n];
    }
}

// ---------------------------------------------------------------------------
extern "C" void kernel_launch(void* const* d_in, const int* in_sizes, int n_in,
                              void* d_out, int out_size, void* d_ws, size_t ws_size,
                              hipStream_t stream)
{
    const float* x    = (const float*)d_in[0];
    const float* wq   = (const float*)d_in[1];
    const float* wk   = (const float*)d_in[2];
    const float* wv   = (const float*)d_in[3];
    const float* wo   = (const float*)d_in[4];
    const float* w1   = (const float*)d_in[5];
    const float* b1   = (const float*)d_in[6];
    const float* w2   = (const float*)d_in[7];
    const float* b2   = (const float*)d_in[8];
    const float* ln0g = (const float*)d_in[9];
    const float* ln0b = (const float*)d_in[10];
    const float* ln1g = (const float*)d_in[11];
    const float* ln1b = (const float*)d_in[12];
    const float* qw   = (const float*)d_in[13];
    const int* out_idx = (const int*)d_in[14];
    const int* in_idx  = (const int*)d_in[15];
    float* out = (float*)d_out;

    const int NNZ = in_sizes[15];
    const int E   = NNZ / NLON;
    const size_t N64 = (size_t)NSEG * 64;

    float* ws    = (float*)d_ws;
    float* q_pl  = ws;                     // [64][NSEG]
    float* k_pl  = ws + N64;
    float* v_pl  = ws + 2 * N64;
    float* num   = ws + 3 * N64;           // [64][NSEG]  (written once by k2)
    float* den   = ws + 4 * N64;           // [4][NSEG]
    float* x1    = ws + 4 * N64 + 4 * NSEG;
    float* m_act = ws + 5 * N64 + 4 * NSEG;           // [128][NSEG]
    int*   row_start = (int*)(ws + 7 * N64 + 4 * NSEG);            // [62]
    int4*  meta  = (int4*)(ws + 7 * N64 + 4 * NSEG + 64);          // [E]

    hipLaunchKernelGGL(k1_ln_qkv, dim3(115, 25), dim3(64), 0, stream,
                       x, wq, wk, wv, ln0g, ln0b, out_idx, in_idx, qw, E,
                       q_pl, k_pl, v_pl, row_start, meta);
    hipLaunchKernelGGL(k2_attn, dim3(61, 4), dim3(512), 0, stream,
                       q_pl, k_pl, v_pl, meta, row_start, num, den);
    hipLaunchKernelGGL(k2c_wo, dim3(115, 8), dim3(64), 0, stream,
                       num, den, wo, x, x1);
    hipLaunchKernelGGL(k3a_mlp1, dim3(115, 8), dim3(64), 0, stream,
                       x1, w1, b1, ln1g, ln1b, m_act);
    hipLaunchKernelGGL(k3b_mlp2, dim3(115, 8), dim3(64), 0, stream,
                       m_act, w2, b2, x1, out);
}